// Round 2
// baseline (269.802 us; speedup 1.0000x reference)
//
#include <hip/hip_runtime.h>

typedef float  f32x4  __attribute__((ext_vector_type(4)));
typedef __bf16 bf16x8 __attribute__((ext_vector_type(8)));
typedef unsigned short u16x4 __attribute__((ext_vector_type(4)));
typedef unsigned short u16x8 __attribute__((ext_vector_type(8)));

#define NL2E  (-1.44269504088896f)   // -log2(e)
#define TL2E  ( 2.88539008177793f)   // 2*log2(e)

__device__ __forceinline__ unsigned short f2bf(float f) {
    unsigned u = __builtin_bit_cast(unsigned, f);
    u = (u + 0x7fffu + ((u >> 16) & 1u)) >> 16;   // RNE
    return (unsigned short)u;
}
// sigmoid(x + b) with nb = -log2e*b precomputed
__device__ __forceinline__ float sigm_pre(float x, float nb) {
    return __builtin_amdgcn_rcpf(1.0f + __builtin_amdgcn_exp2f(__builtin_fmaf(x, NL2E, nb)));
}
// tanh(x + b) with tb = 2*log2e*b precomputed
__device__ __forceinline__ float tanh_pre(float x, float tb) {
    return 1.0f - 2.0f * __builtin_amdgcn_rcpf(1.0f + __builtin_amdgcn_exp2f(__builtin_fmaf(x, TL2E, tb)));
}

// WG: 256 threads = 4 waves, 4 batch elements, all 256 timesteps.
// grid 1024 -> 4 WG/CU (occupancy was the round-1 limiter).
// Wave w computes gate-slice [64w,64w+64) via MFMA (A rows 0..3 = batches,
// rows 4..15 duplicate rows 0..3 harmlessly); elementwise: lane=hidden, wave=batch.
__global__ __launch_bounds__(256, 4) void lstm_fused(
    const float* __restrict__ x,      // [4096][256][16]
    const float* __restrict__ w_ih1,  // [256][16]
    const float* __restrict__ w_hh1,  // [256][64]
    const float* __restrict__ b_ih1, const float* __restrict__ b_hh1,
    const float* __restrict__ w_ih2,  // [4][64]
    const float* __restrict__ w_hh2,  // [4]
    const float* __restrict__ b_ih2, const float* __restrict__ b_hh2,
    const float* __restrict__ fc_w, const float* __restrict__ fc_b,
    float* __restrict__ out)          // [4096][256]
{
    __shared__ unsigned short A_h[4 * 64];      // h1 bf16 [b][he], byte ^ (b<<4)
    __shared__ unsigned short Xc[4 * 16 * 32];  // x chunk bf16 [b][tt][k] (k>=16 zero), slot ^ (b<<4)
    __shared__ float Pre[4 * 256];              // layer-1 preacts [b][n]
    __shared__ float Pre2[16];                  // layer-2 preacts [b][g]
    __shared__ float Ybuf[64];                  // [b][tt]

    const int tid = threadIdx.x;
    const int wv  = tid >> 6;
    const int l   = tid & 63;
    const int col = l & 15;
    const int hi  = l >> 4;
    const int b0  = blockIdx.x * 4;
    const int he  = l;                          // hidden index for elementwise

    // zero-init LDS (A_h: h0=0; Xc: pad cols stay zero forever)
    if (tid < 32) ((u16x8*)A_h)[tid] = (u16x8){0,0,0,0,0,0,0,0};
    ((u16x8*)Xc)[tid] = (u16x8){0,0,0,0,0,0,0,0};

    // ---- B fragments in registers (loaded once) ----
    // tiles c=0..3: n = wv*64 + c*16 + col; k 0..63 = W_hh1[n][k], 64..79 = W_ih1, 80..95 = 0
    // tile 4 (wave 3): layer-2 input proj, col<4 -> w_ih2 rows, k<64
    bf16x8 Bf[5][3];
    #pragma unroll
    for (int c = 0; c < 5; ++c) {
        const int n = (c < 4 ? (wv * 64 + c * 16) : 0) + col;
        #pragma unroll
        for (int ks = 0; ks < 3; ++ks) {
            u16x8 tmp;
            #pragma unroll
            for (int j = 0; j < 8; ++j) {
                const int k = ks * 32 + hi * 8 + j;
                float v = 0.0f;
                if (c < 4) {
                    if (k < 64)      v = w_hh1[n * 64 + k];
                    else if (k < 80) v = w_ih1[n * 16 + (k - 64)];
                } else {
                    if (col < 4 && k < 64) v = w_ih2[col * 64 + k];
                }
                tmp[j] = f2bf(v);
            }
            Bf[c][ks] = __builtin_bit_cast(bf16x8, tmp);
        }
    }

    // layer-1 bias constants folded into exp2 argument (lane he)
    const float nbi = NL2E * (b_ih1[he]       + b_hh1[he]);
    const float nbf = NL2E * (b_ih1[64 + he]  + b_hh1[64 + he]);
    const float tbg = TL2E * (b_ih1[128 + he] + b_hh1[128 + he]);
    const float nbo = NL2E * (b_ih1[192 + he] + b_hh1[192 + he]);

    // layer-2 constants (uniform -> s-loads)
    const float w2i = w_hh2[0], w2f = w_hh2[1], w2g = w_hh2[2], w2o = w_hh2[3];
    const float nb2i = NL2E * (b_ih2[0] + b_hh2[0]);
    const float nb2f = NL2E * (b_ih2[1] + b_hh2[1]);
    const float tb2g = TL2E * (b_ih2[2] + b_hh2[2]);
    const float nb2o = NL2E * (b_ih2[3] + b_hh2[3]);
    const float fcw = fc_w[0], fcb = fc_b[0];

    // invariant LDS addresses
    const int rb = col & 3;                     // A row (batch) this lane reads
    const char* ah_rd = (const char*)A_h + rb * 128  + ((hi * 16) ^ (rb << 4));
    const char* xc_rd = (const char*)Xc  + rb * 1024 + ((hi * 16) ^ (rb << 4));
    unsigned short* ah_wr = (unsigned short*)((char*)A_h + wv * 128 + ((he * 2) ^ (wv << 4)));
    char* xc_st = (char*)Xc + wv * 1024 + ((tid >> 2) & 15) * 64 + (((tid & 3) * 8) ^ (wv << 4));

    // x prefetch: thread owns x[b0+wv][t0 + (tid>>2)&15][(tid&3)*4 ..+3]
    const float* xrow = x + (size_t)(b0 + wv) * (256 * 16) + ((tid >> 2) & 15) * 16 + (tid & 3) * 4;
    f32x4 xq = *(const f32x4*)xrow;

    float c1 = 0.f, h2 = 0.f, c2 = 0.f;

    __syncthreads();   // init + first-chunk regs ready; Xc zeros visible

    for (int t = 0; t < 256; ++t) {
        const int tt = t & 15;
        if (tt == 0) {
            u16x4 xb;
            xb[0] = f2bf(xq[0]); xb[1] = f2bf(xq[1]); xb[2] = f2bf(xq[2]); xb[3] = f2bf(xq[3]);
            *(u16x4*)xc_st = xb;
            if (t + 16 < 256) xq = *(const f32x4*)(xrow + (t + 16) * 16);  // 16 steps of slack
        }
        __syncthreads();   // barrier A: A_h(t-1) writes + Xc chunk visible

        bf16x8 a0 = __builtin_bit_cast(bf16x8, *(const u16x8*)(ah_rd));
        bf16x8 a1 = __builtin_bit_cast(bf16x8, *(const u16x8*)(ah_rd + 64));
        bf16x8 a2 = __builtin_bit_cast(bf16x8, *(const u16x8*)(xc_rd + tt * 64));

        #pragma unroll
        for (int c = 0; c < 4; ++c) {
            f32x4 acc = {0.f, 0.f, 0.f, 0.f};
            acc = __builtin_amdgcn_mfma_f32_16x16x32_bf16(a0, Bf[c][0], acc, 0, 0, 0);
            acc = __builtin_amdgcn_mfma_f32_16x16x32_bf16(a1, Bf[c][1], acc, 0, 0, 0);
            acc = __builtin_amdgcn_mfma_f32_16x16x32_bf16(a2, Bf[c][2], acc, 0, 0, 0);
            if (hi == 0) {   // rows 0..3 = real batches
                const int n = wv * 64 + c * 16 + col;
                #pragma unroll
                for (int r = 0; r < 4; ++r) Pre[r * 256 + n] = acc[r];
            }
        }
        if (wv == 3) {   // layer-2 input projection of h1_{t-1}
            f32x4 acc = {0.f, 0.f, 0.f, 0.f};
            acc = __builtin_amdgcn_mfma_f32_16x16x32_bf16(a0, Bf[4][0], acc, 0, 0, 0);
            acc = __builtin_amdgcn_mfma_f32_16x16x32_bf16(a1, Bf[4][1], acc, 0, 0, 0);
            if (hi == 0 && col < 4) {
                #pragma unroll
                for (int r = 0; r < 4; ++r) Pre2[r * 4 + col] = acc[r];
            }
        }
        __syncthreads();   // barrier B: Pre/Pre2 visible

        // ---- layer-1 elementwise: 1 cell per lane (batch wv, hidden he) ----
        const float P0 = Pre[wv * 256 + he];
        const float P1 = Pre[wv * 256 + 64 + he];
        const float P2 = Pre[wv * 256 + 128 + he];
        const float P3 = Pre[wv * 256 + 192 + he];
        const float iv = sigm_pre(P0, nbi);
        const float fv = sigm_pre(P1, nbf);
        const float gv = tanh_pre(P2, tbg);
        const float ov = sigm_pre(P3, nbo);
        const float cn = __builtin_fmaf(fv, c1, iv * gv);
        c1 = cn;
        *ah_wr = f2bf(ov * tanh_pre(cn, 0.f));

        // ---- layer-2 + FC (one step behind), wave 0 lanes 0..3 (lane = batch) ----
        if (wv == 0 && t > 0) {
            const int s = t - 1;
            if (l < 4) {
                const f32x4 p2 = *(const f32x4*)&Pre2[l * 4];
                const float i2 = sigm_pre(__builtin_fmaf(w2i, h2, p2[0]), nb2i);
                const float f2 = sigm_pre(__builtin_fmaf(w2f, h2, p2[1]), nb2f);
                const float g2 = tanh_pre(__builtin_fmaf(w2g, h2, p2[2]), tb2g);
                const float o2 = sigm_pre(__builtin_fmaf(w2o, h2, p2[3]), nb2o);
                c2 = __builtin_fmaf(f2, c2, i2 * g2);
                h2 = o2 * tanh_pre(c2, 0.f);
                Ybuf[l * 16 + (s & 15)] = __builtin_fmaf(fcw, h2, fcb);
            }
            if ((s & 15) == 15) {   // coalesced flush: 4 rows x 64B
                out[(size_t)(b0 + (l >> 4)) * 256 + (s - 15) + (l & 15)] = Ybuf[l];
            }
        }
    }

    // ---- epilogue: layer-2 step for s = 255 ----
    __syncthreads();   // h1_255 in A_h visible
    if (wv == 3) {
        bf16x8 a0 = __builtin_bit_cast(bf16x8, *(const u16x8*)(ah_rd));
        bf16x8 a1 = __builtin_bit_cast(bf16x8, *(const u16x8*)(ah_rd + 64));
        f32x4 acc = {0.f, 0.f, 0.f, 0.f};
        acc = __builtin_amdgcn_mfma_f32_16x16x32_bf16(a0, Bf[4][0], acc, 0, 0, 0);
        acc = __builtin_amdgcn_mfma_f32_16x16x32_bf16(a1, Bf[4][1], acc, 0, 0, 0);
        if (hi == 0 && col < 4) {
            #pragma unroll
            for (int r = 0; r < 4; ++r) Pre2[r * 4 + col] = acc[r];
        }
    }
    __syncthreads();
    if (wv == 0) {
        if (l < 4) {
            const f32x4 p2 = *(const f32x4*)&Pre2[l * 4];
            const float i2 = sigm_pre(__builtin_fmaf(w2i, h2, p2[0]), nb2i);
            const float f2 = sigm_pre(__builtin_fmaf(w2f, h2, p2[1]), nb2f);
            const float g2 = tanh_pre(__builtin_fmaf(w2g, h2, p2[2]), tb2g);
            const float o2 = sigm_pre(__builtin_fmaf(w2o, h2, p2[3]), nb2o);
            c2 = __builtin_fmaf(f2, c2, i2 * g2);
            h2 = o2 * tanh_pre(c2, 0.f);
            Ybuf[l * 16 + 15] = __builtin_fmaf(fcw, h2, fcb);
        }
        out[(size_t)(b0 + (l >> 4)) * 256 + 240 + (l & 15)] = Ybuf[l];
    }
}

extern "C" void kernel_launch(void* const* d_in, const int* in_sizes, int n_in,
                              void* d_out, int out_size, void* d_ws, size_t ws_size,
                              hipStream_t stream) {
    const float* x     = (const float*)d_in[0];
    const float* w_ih1 = (const float*)d_in[1];
    const float* w_hh1 = (const float*)d_in[2];
    const float* b_ih1 = (const float*)d_in[3];
    const float* b_hh1 = (const float*)d_in[4];
    const float* w_ih2 = (const float*)d_in[5];
    const float* w_hh2 = (const float*)d_in[6];
    const float* b_ih2 = (const float*)d_in[7];
    const float* b_hh2 = (const float*)d_in[8];
    const float* fc_w  = (const float*)d_in[9];
    const float* fc_b  = (const float*)d_in[10];
    lstm_fused<<<dim3(1024), dim3(256), 0, stream>>>(
        x, w_ih1, w_hh1, b_ih1, b_hh1, w_ih2, w_hh2, b_ih2, b_hh2, fc_w, fc_b,
        (float*)d_out);
}

// Round 3
// 157.036 us; speedup vs baseline: 1.7181x; 1.7181x over previous
//
#include <hip/hip_runtime.h>

typedef float  f32x4  __attribute__((ext_vector_type(4)));
typedef __bf16 bf16x8 __attribute__((ext_vector_type(8)));
typedef unsigned short u16x8 __attribute__((ext_vector_type(8)));

#define NL2E (-1.44269504088896f)   // -log2(e)
#define TL2E ( 2.88539008177793f)   // 2*log2(e)

// z already scaled: sigmoid -> z = -log2e*(x+b), tanh -> z = 2log2e*(x+b)
__device__ __forceinline__ float sigm_z(float z) {
    return __builtin_amdgcn_rcpf(1.0f + __builtin_amdgcn_exp2f(z));
}
__device__ __forceinline__ float tanh_z(float z) {
    return 1.0f - 2.0f * __builtin_amdgcn_rcpf(1.0f + __builtin_amdgcn_exp2f(z));
}

// 16 batches/WG, 4 waves, grid 256 (1 WG/CU). Single barrier per timestep.
// Wave w owns N-tiles {w, w+4, w+8, w+12} -> lane (q,hi) holds ALL 4 gates of
// hidden he=16w+q for batches 4hi+j in its MFMA accs (no Pre LDS round-trip).
// A_h (h state) and Xc (x chunks) double-buffered so one barrier suffices.
__global__ __launch_bounds__(256, 1) void lstm_fused(
    const float* __restrict__ x,      // [4096][256][16]
    const float* __restrict__ w_ih1,  // [256][16]
    const float* __restrict__ w_hh1,  // [256][64]
    const float* __restrict__ b_ih1, const float* __restrict__ b_hh1,
    const float* __restrict__ w_ih2,  // [4][64]
    const float* __restrict__ w_hh2,  // [4]
    const float* __restrict__ b_ih2, const float* __restrict__ b_hh2,
    const float* __restrict__ fc_w, const float* __restrict__ fc_b,
    float* __restrict__ out)          // [4096][256]
{
    __shared__ unsigned short A_h[2 * 16 * 64];        // 4KB: dbuf h1 bf16 [buf][b][he], ^((b&7)<<4)
    __shared__ unsigned short Xc[2 * 16 * 16 * 32];    // 32KB: dbuf x bf16 [buf][b][tt][k] (k>=16 zero)
    __shared__ float Pre2[2][64];                      // dbuf layer-2 preacts [buf][b*4+g]

    const int tid = threadIdx.x;
    const int wv  = tid >> 6;
    const int l   = tid & 63;
    const int q   = l & 15;
    const int hi  = l >> 4;
    const int b0  = blockIdx.x << 4;
    const int he  = (wv << 4) + q;
    const int sw  = (q & 7) << 4;

    ((u16x8*)A_h)[tid] = (u16x8){0,0,0,0,0,0,0,0};     // zero both A_h bufs (h_{-1}=0)

    // ---- B fragments, pre-scaled so MFMA acc is directly the exp2 argument ----
    bf16x8 Bf[4][3];
    #pragma unroll
    for (int g = 0; g < 4; ++g) {
        const float sc = (g == 2) ? TL2E : NL2E;
        const int n = (g << 6) + (wv << 4) + q;        // global gate column
        #pragma unroll
        for (int ks = 0; ks < 3; ++ks) {
            bf16x8 tmp;
            #pragma unroll
            for (int j = 0; j < 8; ++j) {
                const int k = ks * 32 + hi * 8 + j;
                float v = 0.f;
                if (k < 64)      v = w_hh1[n * 64 + k];
                else if (k < 80) v = w_ih1[n * 16 + (k - 64)];
                tmp[j] = (__bf16)(sc * v);
            }
            Bf[g][ks] = tmp;
        }
    }
    bf16x8 B2[2];                                      // layer-2 input proj (used by wave 3)
    {
        const float sc2 = (q == 2) ? TL2E : NL2E;
        #pragma unroll
        for (int ks = 0; ks < 2; ++ks) {
            bf16x8 tmp;
            #pragma unroll
            for (int j = 0; j < 8; ++j) {
                const int k = ks * 32 + hi * 8 + j;
                const float v = (q < 4) ? w_ih2[q * 64 + k] : 0.f;
                tmp[j] = (__bf16)(sc2 * v);
            }
            B2[ks] = tmp;
        }
    }

    // layer-1 biases as scaled acc-init values (per lane: hidden he, all 4 batches)
    float accb[4];
    #pragma unroll
    for (int g = 0; g < 4; ++g) {
        const float sc = (g == 2) ? TL2E : NL2E;
        accb[g] = sc * (b_ih1[(g << 6) + he] + b_hh1[(g << 6) + he]);
    }

    // layer-2 constants (scaled)
    const float w2si = NL2E * w_hh2[0], w2sf = NL2E * w_hh2[1];
    const float w2sg = TL2E * w_hh2[2], w2so = NL2E * w_hh2[3];
    const float nb2i = NL2E * (b_ih2[0] + b_hh2[0]);
    const float nb2f = NL2E * (b_ih2[1] + b_hh2[1]);
    const float tb2g = TL2E * (b_ih2[2] + b_hh2[2]);
    const float nb2o = NL2E * (b_ih2[3] + b_hh2[3]);
    const float fcw = fc_w[0], fcb = fc_b[0];

    // ---- x staging: thread (bx,part) owns x[b0+bx][t0+part][0..15] ----
    const int bx = tid >> 4, part = tid & 15;
    const int swx = (bx & 7) << 4;
    const unsigned xo0 = (unsigned)(bx * 1024 + (((part << 6) +  0) ^ swx));
    const unsigned xo1 = (unsigned)(bx * 1024 + (((part << 6) + 16) ^ swx));
    const unsigned xo2 = (unsigned)(bx * 1024 + (((part << 6) + 32) ^ swx));
    const unsigned xo3 = (unsigned)(bx * 1024 + (((part << 6) + 48) ^ swx));
    const float* xrow = x + (size_t)(b0 + bx) * 4096 + part * 16;

    f32x4 xq0, xq1, xq2, xq3;
    auto stage_x = [&](int bufoff) {
        bf16x8 lo, hw;
        #pragma unroll
        for (int j = 0; j < 4; ++j) {
            lo[j] = (__bf16)xq0[j]; lo[4 + j] = (__bf16)xq1[j];
            hw[j] = (__bf16)xq2[j]; hw[4 + j] = (__bf16)xq3[j];
        }
        const u16x8 z = {0,0,0,0,0,0,0,0};
        char* base = (char*)Xc + bufoff;
        *(u16x8*)(base + xo0) = __builtin_bit_cast(u16x8, lo);
        *(u16x8*)(base + xo1) = __builtin_bit_cast(u16x8, hw);
        *(u16x8*)(base + xo2) = z;
        *(u16x8*)(base + xo3) = z;
    };

    // prologue: stage chunk 0 into buf 0, then prefetch chunk 1 into regs
    xq0 = ((const f32x4*)xrow)[0]; xq1 = ((const f32x4*)xrow)[1];
    xq2 = ((const f32x4*)xrow)[2]; xq3 = ((const f32x4*)xrow)[3];
    stage_x(0);
    {
        const float* p = xrow + 256;
        xq0 = ((const f32x4*)p)[0]; xq1 = ((const f32x4*)p)[1];
        xq2 = ((const f32x4*)p)[2]; xq3 = ((const f32x4*)p)[3];
    }

    // invariant addresses
    const unsigned ar0 = (unsigned)((q * 128 +      hi * 16) ^ sw);   // h k-chunk 0
    const unsigned ar1 = (unsigned)((q * 128 + 64 + hi * 16) ^ sw);   // h k-chunk 1
    unsigned awb[4];
    #pragma unroll
    for (int j = 0; j < 4; ++j) {
        const int b = (hi << 2) + j;
        awb[j] = (unsigned)(b * 128 + ((he * 2) ^ ((b & 7) << 4)));
    }

    f32x4 c1 = {0.f, 0.f, 0.f, 0.f};
    float h2 = 0.f, c2 = 0.f;

    __syncthreads();

    #pragma unroll 2
    for (int t = 0; t < 256; ++t) {
        const int tt = t & 15;
        if (tt == 0 && t + 16 < 256) {
            stage_x(((((t >> 4) + 1) & 1)) << 14);    // chunk k+1 -> idle buf (16KB stride)
            if (t + 32 < 256) {
                const float* p = xrow + (t + 32) * 16;
                xq0 = ((const f32x4*)p)[0]; xq1 = ((const f32x4*)p)[1];
                xq2 = ((const f32x4*)p)[2]; xq3 = ((const f32x4*)p)[3];
            }
        }

        // A-fragment reads: h_{t-1} from buf (t-1)&1, x from current chunk buf
        const int rb = ((t + 1) & 1) << 11;
        const u16x8 ra0 = *(const u16x8*)((const char*)A_h + rb + ar0);
        const u16x8 ra1 = *(const u16x8*)((const char*)A_h + rb + ar1);
        const u16x8 ra2 = *(const u16x8*)((const char*)Xc + (((t >> 4) & 1) << 14)
                                          + ((q * 1024 + (tt << 6) + (hi << 4)) ^ sw));

        // layer-2 + FC at lag 2 (wave 1, lanes 0..15 = batches); overlaps ds latency
        if (wv == 1 && t >= 2 && l < 16) {
            const f32x4 p2 = *(const f32x4*)&Pre2[(t + 1) & 1][l << 2];
            const float zi = p2[0] + __builtin_fmaf(w2si, h2, nb2i);
            const float zf = p2[1] + __builtin_fmaf(w2sf, h2, nb2f);
            const float zg = p2[2] + __builtin_fmaf(w2sg, h2, tb2g);
            const float zo = p2[3] + __builtin_fmaf(w2so, h2, nb2o);
            const float i2 = sigm_z(zi), f2v = sigm_z(zf);
            const float g2v = tanh_z(zg), o2 = sigm_z(zo);
            c2 = __builtin_fmaf(f2v, c2, i2 * g2v);
            h2 = o2 * tanh_z(c2 * TL2E);
            out[(size_t)(b0 + l) * 256 + (t - 2)] = __builtin_fmaf(fcw, h2, fcb);
        }

        const bf16x8 a0 = __builtin_bit_cast(bf16x8, ra0);
        const bf16x8 a1 = __builtin_bit_cast(bf16x8, ra1);
        const bf16x8 a2 = __builtin_bit_cast(bf16x8, ra2);

        f32x4 g0 = {accb[0], accb[0], accb[0], accb[0]};
        f32x4 g1 = {accb[1], accb[1], accb[1], accb[1]};
        f32x4 g2 = {accb[2], accb[2], accb[2], accb[2]};
        f32x4 g3 = {accb[3], accb[3], accb[3], accb[3]};
        g0 = __builtin_amdgcn_mfma_f32_16x16x32_bf16(a0, Bf[0][0], g0, 0, 0, 0);
        g1 = __builtin_amdgcn_mfma_f32_16x16x32_bf16(a0, Bf[1][0], g1, 0, 0, 0);
        g2 = __builtin_amdgcn_mfma_f32_16x16x32_bf16(a0, Bf[2][0], g2, 0, 0, 0);
        g3 = __builtin_amdgcn_mfma_f32_16x16x32_bf16(a0, Bf[3][0], g3, 0, 0, 0);
        g0 = __builtin_amdgcn_mfma_f32_16x16x32_bf16(a1, Bf[0][1], g0, 0, 0, 0);
        g1 = __builtin_amdgcn_mfma_f32_16x16x32_bf16(a1, Bf[1][1], g1, 0, 0, 0);
        g2 = __builtin_amdgcn_mfma_f32_16x16x32_bf16(a1, Bf[2][1], g2, 0, 0, 0);
        g3 = __builtin_amdgcn_mfma_f32_16x16x32_bf16(a1, Bf[3][1], g3, 0, 0, 0);
        g0 = __builtin_amdgcn_mfma_f32_16x16x32_bf16(a2, Bf[0][2], g0, 0, 0, 0);
        g1 = __builtin_amdgcn_mfma_f32_16x16x32_bf16(a2, Bf[1][2], g1, 0, 0, 0);
        g2 = __builtin_amdgcn_mfma_f32_16x16x32_bf16(a2, Bf[2][2], g2, 0, 0, 0);
        g3 = __builtin_amdgcn_mfma_f32_16x16x32_bf16(a2, Bf[3][2], g3, 0, 0, 0);

        if (wv == 3) {   // layer-2 input projection of h_{t-1} -> Pre2[t&1]
            f32x4 p4 = {0.f, 0.f, 0.f, 0.f};
            p4 = __builtin_amdgcn_mfma_f32_16x16x32_bf16(a0, B2[0], p4, 0, 0, 0);
            p4 = __builtin_amdgcn_mfma_f32_16x16x32_bf16(a1, B2[1], p4, 0, 0, 0);
            if (q < 4) {
                #pragma unroll
                for (int r = 0; r < 4; ++r) Pre2[t & 1][((hi << 2) + r) * 4 + q] = p4[r];
            }
        }

        // elementwise: accs ARE the scaled preacts; write h_t to buf t&1
        unsigned short* AW = (unsigned short*)((char*)A_h + ((t & 1) << 11));
        #pragma unroll
        for (int j = 0; j < 4; ++j) {
            const float iv = sigm_z(g0[j]);
            const float fv = sigm_z(g1[j]);
            const float gv = tanh_z(g2[j]);
            const float ov = sigm_z(g3[j]);
            const float cn = __builtin_fmaf(fv, c1[j], iv * gv);
            c1[j] = cn;
            const float hv = ov * tanh_z(cn * TL2E);
            *(unsigned short*)((char*)AW + awb[j]) = __builtin_bit_cast(unsigned short, (__bf16)hv);
        }
        __syncthreads();
    }

    // ---- epilogue: layer-2 steps s=254 (Pre2[1]) and s=255 (fresh proj of h_255) ----
    if (wv == 3) {
        const u16x8 ra0 = *(const u16x8*)((const char*)A_h + 2048 + ar0);
        const u16x8 ra1 = *(const u16x8*)((const char*)A_h + 2048 + ar1);
        f32x4 p4 = {0.f, 0.f, 0.f, 0.f};
        p4 = __builtin_amdgcn_mfma_f32_16x16x32_bf16(__builtin_bit_cast(bf16x8, ra0), B2[0], p4, 0, 0, 0);
        p4 = __builtin_amdgcn_mfma_f32_16x16x32_bf16(__builtin_bit_cast(bf16x8, ra1), B2[1], p4, 0, 0, 0);
        if (q < 4) {
            #pragma unroll
            for (int r = 0; r < 4; ++r) Pre2[0][((hi << 2) + r) * 4 + q] = p4[r];
        }
    }
    if (wv == 1 && l < 16) {   // s = 254 from Pre2[1] (written at t=255)
        const f32x4 p2 = *(const f32x4*)&Pre2[1][l << 2];
        const float zi = p2[0] + __builtin_fmaf(w2si, h2, nb2i);
        const float zf = p2[1] + __builtin_fmaf(w2sf, h2, nb2f);
        const float zg = p2[2] + __builtin_fmaf(w2sg, h2, tb2g);
        const float zo = p2[3] + __builtin_fmaf(w2so, h2, nb2o);
        const float i2 = sigm_z(zi), f2v = sigm_z(zf);
        const float g2v = tanh_z(zg), o2 = sigm_z(zo);
        c2 = __builtin_fmaf(f2v, c2, i2 * g2v);
        h2 = o2 * tanh_z(c2 * TL2E);
        out[(size_t)(b0 + l) * 256 + 254] = __builtin_fmaf(fcw, h2, fcb);
    }
    __syncthreads();
    if (wv == 1 && l < 16) {   // s = 255 from fresh Pre2[0]
        const f32x4 p2 = *(const f32x4*)&Pre2[0][l << 2];
        const float zi = p2[0] + __builtin_fmaf(w2si, h2, nb2i);
        const float zf = p2[1] + __builtin_fmaf(w2sf, h2, nb2f);
        const float zg = p2[2] + __builtin_fmaf(w2sg, h2, tb2g);
        const float zo = p2[3] + __builtin_fmaf(w2so, h2, nb2o);
        const float i2 = sigm_z(zi), f2v = sigm_z(zf);
        const float g2v = tanh_z(zg), o2 = sigm_z(zo);
        c2 = __builtin_fmaf(f2v, c2, i2 * g2v);
        h2 = o2 * tanh_z(c2 * TL2E);
        out[(size_t)(b0 + l) * 256 + 255] = __builtin_fmaf(fcw, h2, fcb);
    }
}

extern "C" void kernel_launch(void* const* d_in, const int* in_sizes, int n_in,
                              void* d_out, int out_size, void* d_ws, size_t ws_size,
                              hipStream_t stream) {
    (void)in_sizes; (void)n_in; (void)out_size; (void)d_ws; (void)ws_size;
    const float* x     = (const float*)d_in[0];
    const float* w_ih1 = (const float*)d_in[1];
    const float* w_hh1 = (const float*)d_in[2];
    const float* b_ih1 = (const float*)d_in[3];
    const float* b_hh1 = (const float*)d_in[4];
    const float* w_ih2 = (const float*)d_in[5];
    const float* w_hh2 = (const float*)d_in[6];
    const float* b_ih2 = (const float*)d_in[7];
    const float* b_hh2 = (const float*)d_in[8];
    const float* fc_w  = (const float*)d_in[9];
    const float* fc_b  = (const float*)d_in[10];
    lstm_fused<<<dim3(256), dim3(256), 0, stream>>>(
        x, w_ih1, w_hh1, b_ih1, b_hh1, w_ih2, w_hh2, b_ih2, b_hh2, fc_w, fc_b,
        (float*)d_out);
}